// Round 1
// baseline (7920.976 us; speedup 1.0000x reference)
//
#include <hip/hip_runtime.h>
#include <math.h>

#define NGRAPH 512

static inline unsigned grid_for(size_t n, int block = 256) {
    return (unsigned)((n + block - 1) / block);
}

__global__ void fill_kernel(float* __restrict__ p, float v, size_t n) {
    size_t i = blockIdx.x * (size_t)blockDim.x + threadIdx.x;
    if (i < n) p[i] = v;
}

// deg[col[e]] += 1  (deg pre-filled with 1.0 for the self loop)
__global__ void deg_kernel(const int* __restrict__ col, int E, float* __restrict__ deg) {
    size_t i = blockIdx.x * (size_t)blockDim.x + threadIdx.x;
    if (i < (size_t)E) atomicAdd(&deg[col[i]], 1.0f);
}

// in-place deg -> deg^-0.5
__global__ void dinv_kernel(float* __restrict__ d, int n) {
    size_t i = blockIdx.x * (size_t)blockDim.x + threadIdx.x;
    if (i < (size_t)n) d[i] = 1.0f / sqrtf(fmaxf(d[i], 1e-12f));
}

__global__ void coef_kernel(const int* __restrict__ row, const int* __restrict__ col,
                            const float* __restrict__ attr, const float* __restrict__ dinv,
                            float* __restrict__ coef, int E) {
    size_t i = blockIdx.x * (size_t)blockDim.x + threadIdx.x;
    if (i < (size_t)E) coef[i] = dinv[row[i]] * attr[i] * dinv[col[i]];
}

// H[N][Fout] = act(X[N][Fin]) @ W[Fin][Fout]
template <bool RELU_IN>
__global__ void node_gemm(const float* __restrict__ X, const float* __restrict__ W,
                          float* __restrict__ H, int N, int Fin, int Fout) {
    size_t idx = blockIdx.x * (size_t)blockDim.x + threadIdx.x;
    if (idx >= (size_t)N * Fout) return;
    int f = (int)(idx % Fout);
    size_t n = idx / Fout;
    const float* xr = X + n * (size_t)Fin;
    float acc = 0.0f;
    for (int k = 0; k < Fin; ++k) {
        float xv = xr[k];
        if (RELU_IN) xv = fmaxf(xv, 0.0f);
        acc = fmaf(xv, W[(size_t)k * Fout + f], acc);
    }
    H[idx] = acc;
}

// AGG[n][f] = dinv[n]^2 * H[n][f]  (self-loop term, also initializes AGG)
__global__ void self_init_kernel(const float* __restrict__ H, const float* __restrict__ dinv,
                                 float* __restrict__ AGG, int N, int F) {
    size_t idx = blockIdx.x * (size_t)blockDim.x + threadIdx.x;
    if (idx >= (size_t)N * F) return;
    size_t n = idx / F;
    float s = dinv[n];
    AGG[idx] = H[idx] * s * s;
}

// AGG[col[e]][f] += coef[e] * H[row[e]][f]
__global__ void scatter_kernel(const int* __restrict__ row, const int* __restrict__ col,
                               const float* __restrict__ coef, const float* __restrict__ H,
                               float* __restrict__ AGG, int E, int F) {
    size_t idx = blockIdx.x * (size_t)blockDim.x + threadIdx.x;
    if (idx >= (size_t)E * F) return;
    size_t e = idx / F;
    int f = (int)(idx % F);
    float v = coef[e] * H[(size_t)row[e] * F + f];
    atomicAdd(&AGG[(size_t)col[e] * F + f], v);
}

// sums[batch[n]][f] += relu(X[n][f]); cnt[batch[n]] += 1 (once per node)
__global__ void pool_sum_kernel(const float* __restrict__ X, const int* __restrict__ batch,
                                float* __restrict__ sums, float* __restrict__ cnt, int N, int F) {
    size_t idx = blockIdx.x * (size_t)blockDim.x + threadIdx.x;
    if (idx >= (size_t)N * F) return;
    size_t n = idx / F;
    int f = (int)(idx % F);
    int g = batch[n];
    atomicAdd(&sums[(size_t)g * F + f], fmaxf(X[idx], 0.0f));
    if (f == 0) atomicAdd(&cnt[g], 1.0f);
}

__global__ void pool_div_kernel(float* __restrict__ sums, const float* __restrict__ cnt, int F) {
    size_t idx = blockIdx.x * (size_t)blockDim.x + threadIdx.x;
    if (idx >= (size_t)NGRAPH * F) return;
    sums[idx] /= fmaxf(cnt[idx / F], 1.0f);
}

// C[g][coff+m] = act(A[g][K] @ W[K][M] + b[m]), C row stride ldc
template <bool RELU_OUT>
__global__ void mlp_gemm(const float* __restrict__ A, const float* __restrict__ W,
                         const float* __restrict__ b, float* __restrict__ C,
                         int K, int M, int ldc, int coff) {
    size_t idx = blockIdx.x * (size_t)blockDim.x + threadIdx.x;
    if (idx >= (size_t)NGRAPH * M) return;
    int m = (int)(idx % M);
    size_t g = idx / M;
    const float* ar = A + g * (size_t)K;
    float acc = b[m];
    for (int k = 0; k < K; ++k) acc = fmaf(ar[k], W[(size_t)k * M + m], acc);
    if (RELU_OUT) acc = fmaxf(acc, 0.0f);
    C[g * (size_t)ldc + coff + m] = acc;
}

// out[g] = A[g][K] . w[K] + b[0]
__global__ void final_kernel(const float* __restrict__ A, const float* __restrict__ w,
                             const float* __restrict__ b, float* __restrict__ out, int K) {
    int g = blockIdx.x * blockDim.x + threadIdx.x;
    if (g >= NGRAPH) return;
    float acc = b[0];
    const float* ar = A + (size_t)g * K;
    for (int k = 0; k < K; ++k) acc = fmaf(ar[k], w[k], acc);
    out[g] = acc;
}

extern "C" void kernel_launch(void* const* d_in, const int* in_sizes, int n_in,
                              void* d_out, int out_size, void* d_ws, size_t ws_size,
                              hipStream_t stream) {
    const float* drug_x  = (const float*)d_in[0];
    const int*   d_ei    = (const int*)d_in[1];
    const float* d_ea    = (const float*)d_in[2];
    const int*   d_batch = (const int*)d_in[3];
    const float* prot_x  = (const float*)d_in[4];
    const int*   p_ei    = (const int*)d_in[5];
    const float* p_ea    = (const float*)d_in[6];
    const int*   p_batch = (const int*)d_in[7];
    const float* dW1 = (const float*)d_in[8];
    const float* dW2 = (const float*)d_in[9];
    const float* dW3 = (const float*)d_in[10];
    const float* dL1_w = (const float*)d_in[11];
    const float* dL1_b = (const float*)d_in[12];
    const float* dL2_w = (const float*)d_in[13];
    const float* dL2_b = (const float*)d_in[14];
    const float* pW1 = (const float*)d_in[15];
    const float* pW2 = (const float*)d_in[16];
    const float* pW3 = (const float*)d_in[17];
    const float* pL1_w = (const float*)d_in[18];
    const float* pL1_b = (const float*)d_in[19];
    const float* pL2_w = (const float*)d_in[20];
    const float* pL2_b = (const float*)d_in[21];
    const float* fW1 = (const float*)d_in[22];
    const float* fb1 = (const float*)d_in[23];
    const float* fW2 = (const float*)d_in[24];
    const float* fb2 = (const float*)d_in[25];
    const float* fW3 = (const float*)d_in[26];
    const float* fb3 = (const float*)d_in[27];
    float* out = (float*)d_out;

    const int Nd = in_sizes[0] / 78;
    const int Ed = in_sizes[1] / 2;
    const int Np = in_sizes[4] / 20;
    const int Ep = in_sizes[5] / 2;
    const int* d_row = d_ei;
    const int* d_col = d_ei + Ed;
    const int* p_row = p_ei;
    const int* p_col = p_ei + Ep;

    // ---- workspace layout (floats) ----
    float* ws = (float*)d_ws;
    size_t off = 0;
    auto take = [&](size_t n) -> float* {
        float* p = ws + off;
        off += (n + 255) & ~(size_t)255;
        return p;
    };
    float* B1     = take((size_t)Nd * 312);  // gemm output H (reused for protein)
    float* B2     = take((size_t)Nd * 312);  // aggregate output (reused for protein)
    float* dinv_d = take((size_t)Nd);
    float* dinv_p = take((size_t)Np);
    float* coef_d = take((size_t)Ed);
    float* coef_p = take((size_t)Ep);
    float* pool   = take((size_t)NGRAPH * 312);
    float* cnt    = take((size_t)NGRAPH);
    float* t1     = take((size_t)NGRAPH * 1024);
    float* Cbuf   = take((size_t)NGRAPH * 128);
    float* f2buf  = take((size_t)NGRAPH * 512);
    (void)ws_size;

    const int B = 256;

    // ---- degree / dinv / edge coefficients (shared across the 3 conv layers) ----
    fill_kernel<<<grid_for(Nd), B, 0, stream>>>(dinv_d, 1.0f, (size_t)Nd);
    deg_kernel<<<grid_for(Ed), B, 0, stream>>>(d_col, Ed, dinv_d);
    dinv_kernel<<<grid_for(Nd), B, 0, stream>>>(dinv_d, Nd);
    coef_kernel<<<grid_for(Ed), B, 0, stream>>>(d_row, d_col, d_ea, dinv_d, coef_d, Ed);

    fill_kernel<<<grid_for(Np), B, 0, stream>>>(dinv_p, 1.0f, (size_t)Np);
    deg_kernel<<<grid_for(Ep), B, 0, stream>>>(p_col, Ep, dinv_p);
    dinv_kernel<<<grid_for(Np), B, 0, stream>>>(dinv_p, Np);
    coef_kernel<<<grid_for(Ep), B, 0, stream>>>(p_row, p_col, p_ea, dinv_p, coef_p, Ep);

    // ---- drug GCN stack: 78 -> 78 -> 156 -> 312 ----
    {
        size_t nf;
        // conv1
        nf = (size_t)Nd * 78;
        node_gemm<false><<<grid_for(nf), B, 0, stream>>>(drug_x, dW1, B1, Nd, 78, 78);
        self_init_kernel<<<grid_for(nf), B, 0, stream>>>(B1, dinv_d, B2, Nd, 78);
        scatter_kernel<<<grid_for((size_t)Ed * 78), B, 0, stream>>>(d_row, d_col, coef_d, B1, B2, Ed, 78);
        // conv2 (relu on input)
        nf = (size_t)Nd * 156;
        node_gemm<true><<<grid_for(nf), B, 0, stream>>>(B2, dW2, B1, Nd, 78, 156);
        self_init_kernel<<<grid_for(nf), B, 0, stream>>>(B1, dinv_d, B2, Nd, 156);
        scatter_kernel<<<grid_for((size_t)Ed * 156), B, 0, stream>>>(d_row, d_col, coef_d, B1, B2, Ed, 156);
        // conv3
        nf = (size_t)Nd * 312;
        node_gemm<true><<<grid_for(nf), B, 0, stream>>>(B2, dW3, B1, Nd, 156, 312);
        self_init_kernel<<<grid_for(nf), B, 0, stream>>>(B1, dinv_d, B2, Nd, 312);
        scatter_kernel<<<grid_for((size_t)Ed * 312), B, 0, stream>>>(d_row, d_col, coef_d, B1, B2, Ed, 312);
        // mean pool (relu inside)
        fill_kernel<<<grid_for((size_t)NGRAPH * 312), B, 0, stream>>>(pool, 0.0f, (size_t)NGRAPH * 312);
        fill_kernel<<<grid_for(NGRAPH), B, 0, stream>>>(cnt, 0.0f, (size_t)NGRAPH);
        pool_sum_kernel<<<grid_for(nf), B, 0, stream>>>(B2, d_batch, pool, cnt, Nd, 312);
        pool_div_kernel<<<grid_for((size_t)NGRAPH * 312), B, 0, stream>>>(pool, cnt, 312);
        // drug MLP -> Cbuf[:, 0:64]
        mlp_gemm<true><<<grid_for((size_t)NGRAPH * 1024), B, 0, stream>>>(pool, dL1_w, dL1_b, t1, 312, 1024, 1024, 0);
        mlp_gemm<true><<<grid_for((size_t)NGRAPH * 64), B, 0, stream>>>(t1, dL2_w, dL2_b, Cbuf, 1024, 64, 128, 0);
    }

    // ---- protein GCN stack: 20 -> 20 -> 40 -> 80 ----
    {
        size_t nf;
        nf = (size_t)Np * 20;
        node_gemm<false><<<grid_for(nf), B, 0, stream>>>(prot_x, pW1, B1, Np, 20, 20);
        self_init_kernel<<<grid_for(nf), B, 0, stream>>>(B1, dinv_p, B2, Np, 20);
        scatter_kernel<<<grid_for((size_t)Ep * 20), B, 0, stream>>>(p_row, p_col, coef_p, B1, B2, Ep, 20);
        nf = (size_t)Np * 40;
        node_gemm<true><<<grid_for(nf), B, 0, stream>>>(B2, pW2, B1, Np, 20, 40);
        self_init_kernel<<<grid_for(nf), B, 0, stream>>>(B1, dinv_p, B2, Np, 40);
        scatter_kernel<<<grid_for((size_t)Ep * 40), B, 0, stream>>>(p_row, p_col, coef_p, B1, B2, Ep, 40);
        nf = (size_t)Np * 80;
        node_gemm<true><<<grid_for(nf), B, 0, stream>>>(B2, pW3, B1, Np, 40, 80);
        self_init_kernel<<<grid_for(nf), B, 0, stream>>>(B1, dinv_p, B2, Np, 80);
        scatter_kernel<<<grid_for((size_t)Ep * 80), B, 0, stream>>>(p_row, p_col, coef_p, B1, B2, Ep, 80);
        fill_kernel<<<grid_for((size_t)NGRAPH * 80), B, 0, stream>>>(pool, 0.0f, (size_t)NGRAPH * 80);
        fill_kernel<<<grid_for(NGRAPH), B, 0, stream>>>(cnt, 0.0f, (size_t)NGRAPH);
        pool_sum_kernel<<<grid_for(nf), B, 0, stream>>>(B2, p_batch, pool, cnt, Np, 80);
        pool_div_kernel<<<grid_for((size_t)NGRAPH * 80), B, 0, stream>>>(pool, cnt, 80);
        // protein MLP -> Cbuf[:, 64:128]
        mlp_gemm<true><<<grid_for((size_t)NGRAPH * 1024), B, 0, stream>>>(pool, pL1_w, pL1_b, t1, 80, 1024, 1024, 0);
        mlp_gemm<true><<<grid_for((size_t)NGRAPH * 64), B, 0, stream>>>(t1, pL2_w, pL2_b, Cbuf, 1024, 64, 128, 64);
    }

    // ---- head: 128 -> 1024 -> 512 -> 1 ----
    mlp_gemm<true><<<grid_for((size_t)NGRAPH * 1024), B, 0, stream>>>(Cbuf, fW1, fb1, t1, 128, 1024, 1024, 0);
    mlp_gemm<true><<<grid_for((size_t)NGRAPH * 512), B, 0, stream>>>(t1, fW2, fb2, f2buf, 1024, 512, 512, 0);
    final_kernel<<<grid_for(NGRAPH), B, 0, stream>>>(f2buf, fW3, fb3, out, 512);
}